// Round 4
// baseline (897.149 us; speedup 1.0000x reference)
//
#include <hip/hip_runtime.h>
#include <hip/hip_bf16.h>
#include <math.h>

// Problem constants
#define NTOK  131072   // B * H * W
#define NTOKH 65536    // tokens per batch image
#define CD    192
#define HID   768

typedef short bf16x8 __attribute__((ext_vector_type(8)));
typedef float f32x4  __attribute__((ext_vector_type(4)));
typedef float f32x2  __attribute__((ext_vector_type(2)));

__device__ __forceinline__ float bf2f(unsigned short v) {
    union { unsigned int u; float f; } c; c.u = ((unsigned int)v) << 16; return c.f;
}
// RNE bf16 round: bit-identical to __float2bfloat16 for non-NaN, ~4 VALU ops
__device__ __forceinline__ unsigned short f2bf(float f) {
    union { float f; unsigned int u; } c; c.f = f;
    unsigned int r = c.u + 0x7FFFu + ((c.u >> 16) & 1u);
    return (unsigned short)(r >> 16);
}
// XLA/Eigen rational erf approximation (what the JAX reference lowers to).
// ~14 FMA + v_rcp, no branches; max abs err ~1e-6 (far below bf16 rounding).
__device__ __forceinline__ float gelu_f(float x) {
    float t = x * 0.7071067811865476f;
    t = fminf(fmaxf(t, -4.0f), 4.0f);
    float s2 = t * t;
    float p = fmaf(s2, -2.72614225801306e-10f, 2.77068142495902e-08f);
    p = fmaf(s2, p, -2.10102402082508e-06f);
    p = fmaf(s2, p, -5.69250639462346e-05f);
    p = fmaf(s2, p, -7.34990630326855e-04f);
    p = fmaf(s2, p, -2.95459980854025e-03f);
    p = fmaf(s2, p, -1.60960333262415e-02f);
    p = p * t;
    float q = fmaf(s2, -1.45660718464996e-05f, -2.13374055278905e-04f);
    q = fmaf(s2, q, -1.68282697438203e-03f);
    q = fmaf(s2, q, -7.37332916720468e-03f);
    q = fmaf(s2, q, -1.42647390514189e-02f);
    float er = p * __builtin_amdgcn_rcpf(q);
    return 0.5f * x * (1.0f + er);
}

// async global->LDS 16B per lane; LDS dest is wave-uniform base + lane*16 (HW behavior)
__device__ __forceinline__ void gld16(const unsigned short* g, unsigned short* l) {
    __builtin_amdgcn_global_load_lds(
        (const __attribute__((address_space(1))) void*)(unsigned long long)(g),
        (__attribute__((address_space(3))) void*)(unsigned int)(unsigned long long)(l),
        16, 0, 0);
}

// ---------------- LayerNorm: one wave per token, C=192=64*3; bf16 out ----------------
__global__ __launch_bounds__(256) void ln_kernel(const float* __restrict__ x,
                                                 const float* __restrict__ g,
                                                 const float* __restrict__ b,
                                                 unsigned short* __restrict__ out) {
    int tok  = blockIdx.x * 4 + (threadIdx.x >> 6);
    int lane = threadIdx.x & 63;
    const float* xp = x + (size_t)tok * CD;
    float v0 = xp[lane], v1 = xp[lane + 64], v2 = xp[lane + 128];
    float s  = v0 + v1 + v2;
    float s2 = v0 * v0 + v1 * v1 + v2 * v2;
    #pragma unroll
    for (int off = 32; off > 0; off >>= 1) {
        s  += __shfl_xor(s,  off, 64);
        s2 += __shfl_xor(s2, off, 64);
    }
    float mu  = s * (1.0f / 192.0f);
    float var = s2 * (1.0f / 192.0f) - mu * mu;
    float rs  = rsqrtf(var + 1e-5f);
    unsigned short* op = out + (size_t)tok * CD;
    op[lane]       = f2bf((v0 - mu) * rs * g[lane]       + b[lane]);
    op[lane + 64]  = f2bf((v1 - mu) * rs * g[lane + 64]  + b[lane + 64]);
    op[lane + 128] = f2bf((v2 - mu) * rs * g[lane + 128] + b[lane + 128]);
}

// ---------------- weight transpose+cast pre-pass (tiny: 0.39M elems) ----------------
__global__ __launch_bounds__(256) void wconv_kernel(
    const float* __restrict__ wq, const float* __restrict__ wkv,
    const float* __restrict__ wproj, const float* __restrict__ w1f,
    const float* __restrict__ w2f,
    unsigned short* __restrict__ qkvT, unsigned short* __restrict__ projT,
    unsigned short* __restrict__ w1T, unsigned short* __restrict__ w2T)
{
    int i = blockIdx.x * 256 + threadIdx.x;   // 0 .. 147455
    if (i < 288 * 192) {
        int n = i / 192, k = i - n * 192;
        float v = (n < 192) ? wq[(size_t)k * 192 + n] : wkv[(size_t)k * 96 + (n - 192)];
        qkvT[n * 192 + k] = f2bf(v);
    }
    if (i < 192 * 192) {
        int n = i / 192, k = i - n * 192;
        projT[n * 192 + k] = f2bf(wproj[(size_t)k * 192 + n]);
    }
    {   // w1T: [768][192]
        int n = i / 192, k = i - n * 192;
        w1T[n * 192 + k] = f2bf(w1f[(size_t)k * 768 + n]);
    }
    {   // w2T: [192][768]
        int n = i / 768, k = i - n * 768;
        w2T[n * 768 + k] = f2bf(w2f[(size_t)k * 192 + n]);
    }
}

// bijective XCD-aware block swizzle (m204 form); nwg need not be %8
__device__ __forceinline__ void xcd_swz(int gx, int& bx, int& by) {
    int nwg  = gx * (int)gridDim.y;
    int id   = (int)blockIdx.y * gx + (int)blockIdx.x;
    int q    = nwg >> 3, r = nwg & 7;
    int xcd  = id & 7, rest = id >> 3;
    int sw   = (xcd < r ? xcd * (q + 1) : r * (q + 1) + (xcd - r) * q) + rest;
    bx = sw % gx; by = sw / gx;
}

// ---------------- MFMA bf16 GEMM, 128x96 block tile, 4 waves 2x2, BK=64 ----------------
// global_load_lds staging, linear LDS, XOR-swizzle on global source + ds_read addr.
// MODE 0: QKV  q=(acc+b0)*scale -> bf16 O0 [m*192+n], kv=acc+b1 -> bf16 O1 [m*96+n-192]
// MODE 1: PROJ fp32 O0[m*192+n] = acc + b0[n] + addsrc[m*192+n]
// MODE 2: FC1  bf16 O0[m*768+n] = gelu(acc + b0[n])
// MODE 3: FC2  fp32 O0[m*192+n] += acc + b0[n]
template<int MODE>
__global__ __launch_bounds__(256) void mgemm_kernel(
    const unsigned short* __restrict__ A,    // [M][K] bf16
    const unsigned short* __restrict__ WT,   // [Nreal][K] bf16
    const float* __restrict__ b0, const float* __restrict__ b1,
    const float* __restrict__ addsrc,
    void* O0, unsigned short* __restrict__ O1,
    int K, int Nreal)
{
    constexpr int BM = 128, BN = 96, BK = 64;
    __shared__ unsigned short As[BM * BK];   // linear [row][64] (128B rows)
    __shared__ unsigned short Bs[BN * BK];
    const int tid  = threadIdx.x;
    const int wave = tid >> 6, lane = tid & 63;
    const int quad = lane >> 4, l16 = lane & 15;
    const int wm = (wave >> 1) * 64, wn = (wave & 1) * 48;
    int bx, by; xcd_swz(gridDim.x, bx, by);
    const int m0 = by * BM, n0 = bx * BN;

    f32x4 acc[4][3];
    #pragma unroll
    for (int mi = 0; mi < 4; mi++)
        #pragma unroll
        for (int ni = 0; ni < 3; ni++) acc[mi][ni] = (f32x4){0.f, 0.f, 0.f, 0.f};

    // staging geometry: one gld16 per wave covers 8 rows x 64 k (1 KiB).
    const int r8 = lane >> 3;
    const int sw = ((lane & 7) ^ r8) << 3;       // swizzled 16B slot, in shorts
    const unsigned short* aSrc = A  + (size_t)(m0 + wave * 32 + r8) * K + sw;
    const unsigned short* bSrc = WT + (size_t)(n0 + wave * 24 + r8) * K + sw;
    unsigned short* aDst = &As[(wave * 32) * BK];
    unsigned short* bDst = &Bs[(wave * 24) * BK];

    for (int k0 = 0; k0 < K; k0 += BK) {
        #pragma unroll
        for (int i = 0; i < 4; i++)               // A: 32 rows per wave
            gld16(aSrc + k0 + i * 8 * K, aDst + i * 8 * BK);
        #pragma unroll
        for (int i = 0; i < 3; i++)               // B: 24 rows per wave
            gld16(bSrc + k0 + i * 8 * K, bDst + i * 8 * BK);
        __syncthreads();

        #pragma unroll
        for (int kk = 0; kk < 2; kk++) {
            const int cb = kk * 64 + quad * 16;   // byte col base within 128B row
            bf16x8 bfr[3];
            #pragma unroll
            for (int ni = 0; ni < 3; ni++) {
                int br = wn + ni * 16 + l16;
                bfr[ni] = *(const bf16x8*)&Bs[br * BK + ((cb ^ ((br & 7) << 4)) >> 1)];
            }
            #pragma unroll
            for (int mi = 0; mi < 4; mi++) {
                int ar = wm + mi * 16 + l16;
                bf16x8 af = *(const bf16x8*)&As[ar * BK + ((cb ^ ((ar & 7) << 4)) >> 1)];
                acc[mi][0] = __builtin_amdgcn_mfma_f32_16x16x32_bf16(af, bfr[0], acc[mi][0], 0, 0, 0);
                acc[mi][1] = __builtin_amdgcn_mfma_f32_16x16x32_bf16(af, bfr[1], acc[mi][1], 0, 0, 0);
                acc[mi][2] = __builtin_amdgcn_mfma_f32_16x16x32_bf16(af, bfr[2], acc[mi][2], 0, 0, 0);
            }
        }
        __syncthreads();
    }

    // epilogue: C/D layout col=lane&15, row=quad*4+reg. Bias hoisted, 32-bit offsets.
    float bc[3], bc1[3];
    #pragma unroll
    for (int ni = 0; ni < 3; ni++) {
        int col = n0 + wn + ni * 16 + l16;
        if (MODE == 0) {
            if (n0 < 192) bc[ni] = b0[col];
            else          bc1[ni] = b1[col - 192];
        } else {
            bc[ni] = b0[col];
        }
    }
    #pragma unroll
    for (int mi = 0; mi < 4; mi++) {
        int row0 = m0 + wm + mi * 16 + quad * 4;
        #pragma unroll
        for (int r = 0; r < 4; r++) {
            unsigned mrow = (unsigned)(row0 + r);
            if (MODE == 0) {
                if (n0 < 192) {
                    unsigned ob = mrow * 192u + (unsigned)(n0 + wn + l16);
                    unsigned short* q0 = (unsigned short*)O0;
                    #pragma unroll
                    for (int ni = 0; ni < 3; ni++)
                        q0[ob + ni * 16] = f2bf((acc[mi][ni][r] + bc[ni]) * 0.17677669529663687f);
                } else {
                    unsigned ob = mrow * 96u + (unsigned)(n0 - 192 + wn + l16);
                    #pragma unroll
                    for (int ni = 0; ni < 3; ni++)
                        O1[ob + ni * 16] = f2bf(acc[mi][ni][r] + bc1[ni]);
                }
            } else if (MODE == 1) {
                unsigned ob = mrow * 192u + (unsigned)(n0 + wn + l16);
                float* op = (float*)O0;
                #pragma unroll
                for (int ni = 0; ni < 3; ni++)
                    op[ob + ni * 16] = acc[mi][ni][r] + bc[ni] + addsrc[ob + ni * 16];
            } else if (MODE == 2) {
                unsigned ob = mrow * 768u + (unsigned)(n0 + wn + l16);
                unsigned short* op = (unsigned short*)O0;
                #pragma unroll
                for (int ni = 0; ni < 3; ni++)
                    op[ob + ni * 16] = f2bf(gelu_f(acc[mi][ni][r] + bc[ni]));
            } else {
                unsigned ob = mrow * 192u + (unsigned)(n0 + wn + l16);
                float* op = (float*)O0;
                #pragma unroll
                for (int ni = 0; ni < 3; ni++)
                    op[ob + ni * 16] = op[ob + ni * 16] + acc[mi][ni][r] + bc[ni];
            }
        }
    }
}

// ---------------- PSA attention: 1 block per 8x8 window, thread = (head, q-token) ----------------
__global__ __launch_bounds__(384) void attn_kernel(
    const unsigned short* __restrict__ q, const unsigned short* __restrict__ kvp,
    const float* __restrict__ bt, unsigned short* __restrict__ aw)
{
    __shared__ float ks[6][16][32];
    __shared__ float vs[6][16][32];
    const int w = blockIdx.x;
    const int b = w >> 10, rem = w & 1023, wh = rem >> 5, wc = rem & 31;
    const int tid = threadIdx.x;
    const size_t base = (size_t)b * 65536;

    for (int e = tid; e < 16 * 192; e += 384) {
        int kk = e / 192, f = e - kk * 192;
        int d1 = kk >> 2, d3 = kk & 3;
        int d2 = f / 96;  int r = f - d2 * 96;
        int d4 = r / 48;  int c4 = r - d4 * 48;
        int i = 2 * d1 + d2, j = 2 * d3 + d4;
        size_t g = base + (size_t)(wh * 8 + i) * 256 + (wc * 8 + j);
        int h = f >> 5, d = f & 31;
        ks[h][kk][d] = bf2f(kvp[g * 96 + c4]);
        vs[h][kk][d] = bf2f(kvp[g * 96 + 48 + c4]);
    }
    __syncthreads();

    const int t = tid & 63, h = tid >> 6;
    const int i = t >> 3, j = t & 7;
    const int iq2 = i >> 1, jq2 = j >> 1;
    const size_t g = base + (size_t)(wh * 8 + i) * 256 + (wc * 8 + j);

    f32x2 qr[16];
    const ushort4* qp = (const ushort4*)(q + g * 192 + h * 32);
    #pragma unroll
    for (int d4i = 0; d4i < 8; d4i++) {
        ushort4 u = qp[d4i];
        qr[d4i * 2 + 0] = (f32x2){bf2f(u.x), bf2f(u.y)};
        qr[d4i * 2 + 1] = (f32x2){bf2f(u.z), bf2f(u.w)};
    }

    float lg[16]; float mx = -1e30f;
    #pragma unroll
    for (int kk = 0; kk < 16; kk++) {
        int kh = kk >> 2, kw = kk & 3;
        const f32x2* kp = (const f32x2*)&ks[h][kk][0];
        f32x2 a2 = (f32x2){bt[((iq2 - kh + 3) * 7 + (jq2 - kw + 3)) * 6 + h], 0.f};
        #pragma unroll
        for (int d = 0; d < 16; d++) a2 = __builtin_elementwise_fma(qr[d], kp[d], a2);
        float s = a2.x + a2.y;
        lg[kk] = s; mx = fmaxf(mx, s);
    }
    float den = 0.f;
    #pragma unroll
    for (int kk = 0; kk < 16; kk++) { lg[kk] = expf(lg[kk] - mx); den += lg[kk]; }
    float inv = 1.0f / den;

    f32x2 oacc[16];
    #pragma unroll
    for (int d = 0; d < 16; d++) oacc[d] = (f32x2){0.f, 0.f};
    #pragma unroll
    for (int kk = 0; kk < 16; kk++) {
        float p = lg[kk] * inv;
        f32x2 pv = (f32x2){p, p};
        const f32x2* vp = (const f32x2*)&vs[h][kk][0];
        #pragma unroll
        for (int d = 0; d < 16; d++) oacc[d] = __builtin_elementwise_fma(pv, vp[d], oacc[d]);
    }
    unsigned int* op = (unsigned int*)(aw + g * 192 + h * 32);
    #pragma unroll
    for (int d = 0; d < 16; d++) {
        unsigned int lo = f2bf(oacc[d].x), hi = f2bf(oacc[d].y);
        op[d] = lo | (hi << 16);
    }
}

// ---- Depthwise 5x5 conv + GELU + residual, one image; register sliding window ----
// Block: 64 ch x (8x8 spatial). Thread: 1 ch x 2 cols x 8 rows.
// LDS tile stored as bf16 (18 KiB) -> 8 blocks/CU = 100% occupancy cap (was 4/50%).
__global__ __launch_bounds__(256, 8) void dwconv_kernel(
    const unsigned short* __restrict__ h1,
    const float* __restrict__ dwk, const float* __restrict__ dwb,
    unsigned short* __restrict__ hout)
{
    __shared__ unsigned short tile[12][12][64];   // bf16, 18432 B
    int bx = blockIdx.x;
    int chb = bx % 12; int t = bx / 12;
    int tw = t % 32; int th = t / 32;
    const int tid = threadIdx.x;
    const int chbase = chb * 64;
    const int ch = tid & 63;
    const int cp = tid >> 6;          // 0..3 -> columns 2cp, 2cp+1
    const int c0 = cp * 2;

    // per-thread weights + bias in registers (tiny, L2-resident)
    float w[25];
    #pragma unroll
    for (int tap = 0; tap < 25; tap++)
        w[tap] = dwk[(size_t)(chbase + ch) * 25 + tap];
    const float bias = dwb[chbase + ch];

    // stage 12x12x64 bf16 tile (zero-padded at image borders) — raw copy, no cvt
    const int lane4 = tid & 15;
    const int pg = tid >> 4;
    for (int p = pg; p < 144; p += 16) {
        int pr = p / 12, pc = p - pr * 12;
        int r = th * 8 - 2 + pr, c = tw * 8 - 2 + pc;
        ushort4 u = make_ushort4(0, 0, 0, 0);
        if (r >= 0 && r < 256 && c >= 0 && c < 256)
            u = *(const ushort4*)(h1 + (((size_t)r * 256 + c) * HID + chbase + lane4 * 4));
        *(ushort4*)&tile[pr][pc][lane4 * 4] = u;
    }
    __syncthreads();

    // sliding 5x6 register window down 8 output rows (scalar FMA — R1 form)
    float win[5][6];
    #pragma unroll
    for (int rr = 0; rr < 4; rr++)
        #pragma unroll
        for (int cc = 0; cc < 6; cc++)
            win[rr][cc] = bf2f(tile[rr][c0 + cc][ch]);

    unsigned obase = ((unsigned)(th * 8) * 256u + (unsigned)(tw * 8 + c0)) * (unsigned)HID
                   + (unsigned)(chbase + ch);

    #pragma unroll
    for (int r0 = 0; r0 < 8; r0++) {
        #pragma unroll
        for (int cc = 0; cc < 6; cc++)
            win[(r0 + 4) % 5][cc] = bf2f(tile[r0 + 4][c0 + cc][ch]);
        float s0 = bias, s1 = bias;
        #pragma unroll
        for (int kr = 0; kr < 5; kr++) {
            int ri = (r0 + kr) % 5;
            #pragma unroll
            for (int kc = 0; kc < 5; kc++) {
                float wt = w[kr * 5 + kc];
                s0 = fmaf(win[ri][kc],     wt, s0);
                s1 = fmaf(win[ri][kc + 1], wt, s1);
            }
        }
        const int rc = (r0 + 2) % 5;
        float v0 = win[rc][2] + gelu_f(s0);
        float v1 = win[rc][3] + gelu_f(s1);
        hout[obase]       = f2bf(v0);
        hout[obase + HID] = f2bf(v1);
        obase += 256u * (unsigned)HID;
    }
}

// ---------------- launch ----------------
extern "C" void kernel_launch(void* const* d_in, const int* in_sizes, int n_in,
                              void* d_out, int out_size, void* d_ws, size_t ws_size,
                              hipStream_t stream) {
    const float* x    = (const float*)d_in[0];
    const float* g1   = (const float*)d_in[1];
    const float* be1  = (const float*)d_in[2];
    const float* wq   = (const float*)d_in[3];
    const float* bq   = (const float*)d_in[4];
    const float* wkv  = (const float*)d_in[5];
    const float* bkv  = (const float*)d_in[6];
    const float* btab = (const float*)d_in[7];
    const float* wproj= (const float*)d_in[8];
    const float* bproj= (const float*)d_in[9];
    const float* g2   = (const float*)d_in[10];
    const float* be2  = (const float*)d_in[11];
    const float* w1f  = (const float*)d_in[12];
    const float* b1f  = (const float*)d_in[13];
    const float* dwk  = (const float*)d_in[14];
    const float* dwb  = (const float*)d_in[15];
    const float* w2f  = (const float*)d_in[16];
    const float* b2f  = (const float*)d_in[17];
    float* out = (float*)d_out;

    // workspace layout (bytes), peak ~327.9 MB
    char* ws = (char*)d_ws;
    unsigned short* xnb  = (unsigned short*)(ws);              // xn -> aw (bf16)
    unsigned short* qb   = (unsigned short*)(ws + 50331648);   // q  -> xn2 (bf16)
    unsigned short* kvb  = (unsigned short*)(ws + 100663296);  // kv (bf16)
    unsigned short* h1b  = (unsigned short*)(ws + 125829120);  // h1, one image (bf16)
    unsigned short* hhb  = (unsigned short*)(ws + 226492416);  // h,  one image (bf16)
    unsigned short* qkvT = (unsigned short*)(ws + 327155712);  // [288][192]
    unsigned short* projT= (unsigned short*)(ws + 327266304);  // [192][192]
    unsigned short* w1T  = (unsigned short*)(ws + 327340032);  // [768][192]
    unsigned short* w2T  = (unsigned short*)(ws + 327634944);  // [192][768]

    // 0) weight transpose+cast
    wconv_kernel<<<576, 256, 0, stream>>>(wq, wkv, wproj, w1f, w2f,
                                          qkvT, projT, w1T, w2T);
    // 1) LN1 -> xnb
    ln_kernel<<<NTOK / 4, 256, 0, stream>>>(x, g1, be1, xnb);
    // 2) QKV projection -> qb, kvb   (N=288 = 3 x 96)
    mgemm_kernel<0><<<dim3(3, NTOK / 128), 256, 0, stream>>>(
        xnb, qkvT, bq, bkv, nullptr, qb, kvb, 192, 288);
    // 3) attention -> aw (token-major), overlays xnb
    attn_kernel<<<2048, 384, 0, stream>>>(qb, kvb, btab, xnb);
    // 4) proj + residual -> xattn lives in d_out   (N=192 = 2 x 96)
    mgemm_kernel<1><<<dim3(2, NTOK / 128), 256, 0, stream>>>(
        xnb, projT, bproj, nullptr, x, out, nullptr, 192, 192);
    // 5) LN2 -> xn2b (overlays qb)
    ln_kernel<<<NTOK / 4, 256, 0, stream>>>(out, g2, be2, qb);
    // 6-8) ConvFFN per batch image; FC2 accumulates into d_out
    for (int half = 0; half < 2; half++) {
        const unsigned short* xn2h = qb + (size_t)half * NTOKH * CD;
        float* outh = out + (size_t)half * NTOKH * CD;
        mgemm_kernel<2><<<dim3(8, NTOKH / 128), 256, 0, stream>>>(
            xn2h, w1T, b1f, nullptr, nullptr, h1b, nullptr, 192, 768);
        dwconv_kernel<<<12 * 32 * 32, 256, 0, stream>>>(h1b, dwk, dwb, hhb);
        mgemm_kernel<3><<<dim3(2, NTOKH / 128), 256, 0, stream>>>(
            hhb, w2T, b2f, nullptr, nullptr, outh, nullptr, 768, 192);
    }
}

// Round 5
// 728.648 us; speedup vs baseline: 1.2313x; 1.2313x over previous
//
#include <hip/hip_runtime.h>
#include <hip/hip_bf16.h>
#include <math.h>

// Problem constants
#define NTOK  131072   // B * H * W
#define NTOKH 65536    // tokens per batch image
#define CD    192
#define HID   768

typedef short bf16x8 __attribute__((ext_vector_type(8)));
typedef float f32x4  __attribute__((ext_vector_type(4)));
typedef float f32x2  __attribute__((ext_vector_type(2)));

__device__ __forceinline__ float bf2f(unsigned short v) {
    union { unsigned int u; float f; } c; c.u = ((unsigned int)v) << 16; return c.f;
}
// RNE bf16 round: bit-identical to __float2bfloat16 for non-NaN, ~4 VALU ops
__device__ __forceinline__ unsigned short f2bf(float f) {
    union { float f; unsigned int u; } c; c.f = f;
    unsigned int r = c.u + 0x7FFFu + ((c.u >> 16) & 1u);
    return (unsigned short)(r >> 16);
}
// XLA/Eigen rational erf approximation (what the JAX reference lowers to).
// ~14 FMA + v_rcp, no branches; max abs err ~1e-6 (far below bf16 rounding).
__device__ __forceinline__ float gelu_f(float x) {
    float t = x * 0.7071067811865476f;
    t = fminf(fmaxf(t, -4.0f), 4.0f);
    float s2 = t * t;
    float p = fmaf(s2, -2.72614225801306e-10f, 2.77068142495902e-08f);
    p = fmaf(s2, p, -2.10102402082508e-06f);
    p = fmaf(s2, p, -5.69250639462346e-05f);
    p = fmaf(s2, p, -7.34990630326855e-04f);
    p = fmaf(s2, p, -2.95459980854025e-03f);
    p = fmaf(s2, p, -1.60960333262415e-02f);
    p = p * t;
    float q = fmaf(s2, -1.45660718464996e-05f, -2.13374055278905e-04f);
    q = fmaf(s2, q, -1.68282697438203e-03f);
    q = fmaf(s2, q, -7.37332916720468e-03f);
    q = fmaf(s2, q, -1.42647390514189e-02f);
    float er = p * __builtin_amdgcn_rcpf(q);
    return 0.5f * x * (1.0f + er);
}

// async global->LDS 16B per lane; LDS dest is wave-uniform base + lane*16 (HW behavior)
__device__ __forceinline__ void gld16(const unsigned short* g, unsigned short* l) {
    __builtin_amdgcn_global_load_lds(
        (const __attribute__((address_space(1))) void*)(unsigned long long)(g),
        (__attribute__((address_space(3))) void*)(unsigned int)(unsigned long long)(l),
        16, 0, 0);
}

// ---------------- LayerNorm: one wave per token, C=192=64*3; bf16 out ----------------
__global__ __launch_bounds__(256) void ln_kernel(const float* __restrict__ x,
                                                 const float* __restrict__ g,
                                                 const float* __restrict__ b,
                                                 unsigned short* __restrict__ out) {
    int tok  = blockIdx.x * 4 + (threadIdx.x >> 6);
    int lane = threadIdx.x & 63;
    const float* xp = x + (size_t)tok * CD;
    float v0 = xp[lane], v1 = xp[lane + 64], v2 = xp[lane + 128];
    float s  = v0 + v1 + v2;
    float s2 = v0 * v0 + v1 * v1 + v2 * v2;
    #pragma unroll
    for (int off = 32; off > 0; off >>= 1) {
        s  += __shfl_xor(s,  off, 64);
        s2 += __shfl_xor(s2, off, 64);
    }
    float mu  = s * (1.0f / 192.0f);
    float var = s2 * (1.0f / 192.0f) - mu * mu;
    float rs  = rsqrtf(var + 1e-5f);
    unsigned short* op = out + (size_t)tok * CD;
    op[lane]       = f2bf((v0 - mu) * rs * g[lane]       + b[lane]);
    op[lane + 64]  = f2bf((v1 - mu) * rs * g[lane + 64]  + b[lane + 64]);
    op[lane + 128] = f2bf((v2 - mu) * rs * g[lane + 128] + b[lane + 128]);
}

// ---------------- weight transpose+cast pre-pass (tiny: 0.39M elems) ----------------
__global__ __launch_bounds__(256) void wconv_kernel(
    const float* __restrict__ wq, const float* __restrict__ wkv,
    const float* __restrict__ wproj, const float* __restrict__ w1f,
    const float* __restrict__ w2f,
    unsigned short* __restrict__ qkvT, unsigned short* __restrict__ projT,
    unsigned short* __restrict__ w1T, unsigned short* __restrict__ w2T)
{
    int i = blockIdx.x * 256 + threadIdx.x;   // 0 .. 147455
    if (i < 288 * 192) {
        int n = i / 192, k = i - n * 192;
        float v = (n < 192) ? wq[(size_t)k * 192 + n] : wkv[(size_t)k * 96 + (n - 192)];
        qkvT[n * 192 + k] = f2bf(v);
    }
    if (i < 192 * 192) {
        int n = i / 192, k = i - n * 192;
        projT[n * 192 + k] = f2bf(wproj[(size_t)k * 192 + n]);
    }
    {   // w1T: [768][192]
        int n = i / 192, k = i - n * 192;
        w1T[n * 192 + k] = f2bf(w1f[(size_t)k * 768 + n]);
    }
    {   // w2T: [192][768]
        int n = i / 768, k = i - n * 768;
        w2T[n * 768 + k] = f2bf(w2f[(size_t)k * 192 + n]);
    }
}

// bijective XCD-aware block swizzle (m204 form); nwg need not be %8
__device__ __forceinline__ void xcd_swz(int gx, int& bx, int& by) {
    int nwg  = gx * (int)gridDim.y;
    int id   = (int)blockIdx.y * gx + (int)blockIdx.x;
    int q    = nwg >> 3, r = nwg & 7;
    int xcd  = id & 7, rest = id >> 3;
    int sw   = (xcd < r ? xcd * (q + 1) : r * (q + 1) + (xcd - r) * q) + rest;
    bx = sw % gx; by = sw / gx;
}

// ---------------- MFMA bf16 GEMM, 128x96 block tile, 4 waves 2x2, BK=64 ----------------
// global_load_lds staging, linear LDS, XOR-swizzle on global source + ds_read addr.
// MODE 0: QKV  q=(acc+b0)*scale -> bf16 O0 [m*192+n], kv=acc+b1 -> bf16 O1 [m*96+n-192]
// MODE 1: PROJ fp32 O0[m*192+n] = acc + b0[n] + addsrc[m*192+n]
// MODE 2: FC1  bf16 O0[m*768+n] = gelu(acc + b0[n])
// MODE 3: FC2  fp32 O0[m*192+n] += acc + b0[n]
template<int MODE>
__global__ __launch_bounds__(256) void mgemm_kernel(
    const unsigned short* __restrict__ A,    // [M][K] bf16
    const unsigned short* __restrict__ WT,   // [Nreal][K] bf16
    const float* __restrict__ b0, const float* __restrict__ b1,
    const float* __restrict__ addsrc,
    void* O0, unsigned short* __restrict__ O1,
    int K, int Nreal)
{
    constexpr int BM = 128, BN = 96, BK = 64;
    __shared__ unsigned short As[BM * BK];   // linear [row][64] (128B rows)
    __shared__ unsigned short Bs[BN * BK];
    const int tid  = threadIdx.x;
    const int wave = tid >> 6, lane = tid & 63;
    const int quad = lane >> 4, l16 = lane & 15;
    const int wm = (wave >> 1) * 64, wn = (wave & 1) * 48;
    int bx, by; xcd_swz(gridDim.x, bx, by);
    const int m0 = by * BM, n0 = bx * BN;

    f32x4 acc[4][3];
    #pragma unroll
    for (int mi = 0; mi < 4; mi++)
        #pragma unroll
        for (int ni = 0; ni < 3; ni++) acc[mi][ni] = (f32x4){0.f, 0.f, 0.f, 0.f};

    // staging geometry: one gld16 per wave covers 8 rows x 64 k (1 KiB).
    const int r8 = lane >> 3;
    const int sw = ((lane & 7) ^ r8) << 3;       // swizzled 16B slot, in shorts
    const unsigned short* aSrc = A  + (size_t)(m0 + wave * 32 + r8) * K + sw;
    const unsigned short* bSrc = WT + (size_t)(n0 + wave * 24 + r8) * K + sw;
    unsigned short* aDst = &As[(wave * 32) * BK];
    unsigned short* bDst = &Bs[(wave * 24) * BK];

    for (int k0 = 0; k0 < K; k0 += BK) {
        #pragma unroll
        for (int i = 0; i < 4; i++)               // A: 32 rows per wave
            gld16(aSrc + k0 + i * 8 * K, aDst + i * 8 * BK);
        #pragma unroll
        for (int i = 0; i < 3; i++)               // B: 24 rows per wave
            gld16(bSrc + k0 + i * 8 * K, bDst + i * 8 * BK);
        __syncthreads();

        #pragma unroll
        for (int kk = 0; kk < 2; kk++) {
            const int cb = kk * 64 + quad * 16;   // byte col base within 128B row
            bf16x8 bfr[3];
            #pragma unroll
            for (int ni = 0; ni < 3; ni++) {
                int br = wn + ni * 16 + l16;
                bfr[ni] = *(const bf16x8*)&Bs[br * BK + ((cb ^ ((br & 7) << 4)) >> 1)];
            }
            #pragma unroll
            for (int mi = 0; mi < 4; mi++) {
                int ar = wm + mi * 16 + l16;
                bf16x8 af = *(const bf16x8*)&As[ar * BK + ((cb ^ ((ar & 7) << 4)) >> 1)];
                acc[mi][0] = __builtin_amdgcn_mfma_f32_16x16x32_bf16(af, bfr[0], acc[mi][0], 0, 0, 0);
                acc[mi][1] = __builtin_amdgcn_mfma_f32_16x16x32_bf16(af, bfr[1], acc[mi][1], 0, 0, 0);
                acc[mi][2] = __builtin_amdgcn_mfma_f32_16x16x32_bf16(af, bfr[2], acc[mi][2], 0, 0, 0);
            }
        }
        __syncthreads();
    }

    // epilogue: C/D layout col=lane&15, row=quad*4+reg. Bias hoisted, 32-bit offsets.
    float bc[3], bc1[3];
    #pragma unroll
    for (int ni = 0; ni < 3; ni++) {
        int col = n0 + wn + ni * 16 + l16;
        if (MODE == 0) {
            if (n0 < 192) bc[ni] = b0[col];
            else          bc1[ni] = b1[col - 192];
        } else {
            bc[ni] = b0[col];
        }
    }
    #pragma unroll
    for (int mi = 0; mi < 4; mi++) {
        int row0 = m0 + wm + mi * 16 + quad * 4;
        #pragma unroll
        for (int r = 0; r < 4; r++) {
            unsigned mrow = (unsigned)(row0 + r);
            if (MODE == 0) {
                if (n0 < 192) {
                    unsigned ob = mrow * 192u + (unsigned)(n0 + wn + l16);
                    unsigned short* q0 = (unsigned short*)O0;
                    #pragma unroll
                    for (int ni = 0; ni < 3; ni++)
                        q0[ob + ni * 16] = f2bf((acc[mi][ni][r] + bc[ni]) * 0.17677669529663687f);
                } else {
                    unsigned ob = mrow * 96u + (unsigned)(n0 - 192 + wn + l16);
                    #pragma unroll
                    for (int ni = 0; ni < 3; ni++)
                        O1[ob + ni * 16] = f2bf(acc[mi][ni][r] + bc1[ni]);
                }
            } else if (MODE == 1) {
                unsigned ob = mrow * 192u + (unsigned)(n0 + wn + l16);
                float* op = (float*)O0;
                #pragma unroll
                for (int ni = 0; ni < 3; ni++)
                    op[ob + ni * 16] = acc[mi][ni][r] + bc[ni] + addsrc[ob + ni * 16];
            } else if (MODE == 2) {
                unsigned ob = mrow * 768u + (unsigned)(n0 + wn + l16);
                unsigned short* op = (unsigned short*)O0;
                #pragma unroll
                for (int ni = 0; ni < 3; ni++)
                    op[ob + ni * 16] = f2bf(gelu_f(acc[mi][ni][r] + bc[ni]));
            } else {
                unsigned ob = mrow * 192u + (unsigned)(n0 + wn + l16);
                float* op = (float*)O0;
                #pragma unroll
                for (int ni = 0; ni < 3; ni++)
                    op[ob + ni * 16] = op[ob + ni * 16] + acc[mi][ni][r] + bc[ni];
            }
        }
    }
}

// ---------------- PSA attention: 1 block per 8x8 window, thread = (head, q-token) ----------------
__global__ __launch_bounds__(384) void attn_kernel(
    const unsigned short* __restrict__ q, const unsigned short* __restrict__ kvp,
    const float* __restrict__ bt, unsigned short* __restrict__ aw)
{
    __shared__ float ks[6][16][32];
    __shared__ float vs[6][16][32];
    const int w = blockIdx.x;
    const int b = w >> 10, rem = w & 1023, wh = rem >> 5, wc = rem & 31;
    const int tid = threadIdx.x;
    const size_t base = (size_t)b * 65536;

    for (int e = tid; e < 16 * 192; e += 384) {
        int kk = e / 192, f = e - kk * 192;
        int d1 = kk >> 2, d3 = kk & 3;
        int d2 = f / 96;  int r = f - d2 * 96;
        int d4 = r / 48;  int c4 = r - d4 * 48;
        int i = 2 * d1 + d2, j = 2 * d3 + d4;
        size_t g = base + (size_t)(wh * 8 + i) * 256 + (wc * 8 + j);
        int h = f >> 5, d = f & 31;
        ks[h][kk][d] = bf2f(kvp[g * 96 + c4]);
        vs[h][kk][d] = bf2f(kvp[g * 96 + 48 + c4]);
    }
    __syncthreads();

    const int t = tid & 63, h = tid >> 6;
    const int i = t >> 3, j = t & 7;
    const int iq2 = i >> 1, jq2 = j >> 1;
    const size_t g = base + (size_t)(wh * 8 + i) * 256 + (wc * 8 + j);

    f32x2 qr[16];
    const ushort4* qp = (const ushort4*)(q + g * 192 + h * 32);
    #pragma unroll
    for (int d4i = 0; d4i < 8; d4i++) {
        ushort4 u = qp[d4i];
        qr[d4i * 2 + 0] = (f32x2){bf2f(u.x), bf2f(u.y)};
        qr[d4i * 2 + 1] = (f32x2){bf2f(u.z), bf2f(u.w)};
    }

    float lg[16]; float mx = -1e30f;
    #pragma unroll
    for (int kk = 0; kk < 16; kk++) {
        int kh = kk >> 2, kw = kk & 3;
        const f32x2* kp = (const f32x2*)&ks[h][kk][0];
        f32x2 a2 = (f32x2){bt[((iq2 - kh + 3) * 7 + (jq2 - kw + 3)) * 6 + h], 0.f};
        #pragma unroll
        for (int d = 0; d < 16; d++) a2 = __builtin_elementwise_fma(qr[d], kp[d], a2);
        float s = a2.x + a2.y;
        lg[kk] = s; mx = fmaxf(mx, s);
    }
    float den = 0.f;
    #pragma unroll
    for (int kk = 0; kk < 16; kk++) { lg[kk] = expf(lg[kk] - mx); den += lg[kk]; }
    float inv = 1.0f / den;

    f32x2 oacc[16];
    #pragma unroll
    for (int d = 0; d < 16; d++) oacc[d] = (f32x2){0.f, 0.f};
    #pragma unroll
    for (int kk = 0; kk < 16; kk++) {
        float p = lg[kk] * inv;
        f32x2 pv = (f32x2){p, p};
        const f32x2* vp = (const f32x2*)&vs[h][kk][0];
        #pragma unroll
        for (int d = 0; d < 16; d++) oacc[d] = __builtin_elementwise_fma(pv, vp[d], oacc[d]);
    }
    unsigned int* op = (unsigned int*)(aw + g * 192 + h * 32);
    #pragma unroll
    for (int d = 0; d < 16; d++) {
        unsigned int lo = f2bf(oacc[d].x), hi = f2bf(oacc[d].y);
        op[d] = lo | (hi << 16);
    }
}

// ---- Depthwise 5x5 conv + GELU + residual, one image; register sliding window ----
// Block: 64 ch x (8x8 spatial). Thread: 1 ch x 2 cols x 8 rows.
// bf16 LDS tile (18432 B) -> LDS allows 8 blocks/CU; NO waves-per-EU floor
// (R4's ",8" forced a 32-VGPR cap -> scratch spills -> 3x HBM traffic).
__global__ __launch_bounds__(256) void dwconv_kernel(
    const unsigned short* __restrict__ h1,
    const float* __restrict__ dwk, const float* __restrict__ dwb,
    unsigned short* __restrict__ hout)
{
    __shared__ unsigned short tile[12][12][64];   // bf16, 18432 B
    int bx = blockIdx.x;
    int chb = bx % 12; int t = bx / 12;
    int tw = t % 32; int th = t / 32;
    const int tid = threadIdx.x;
    const int chbase = chb * 64;
    const int ch = tid & 63;
    const int cp = tid >> 6;          // 0..3 -> columns 2cp, 2cp+1
    const int c0 = cp * 2;

    // per-thread weights + bias in registers (tiny, L2-resident)
    float w[25];
    #pragma unroll
    for (int tap = 0; tap < 25; tap++)
        w[tap] = dwk[(size_t)(chbase + ch) * 25 + tap];
    const float bias = dwb[chbase + ch];

    // stage 12x12x64 bf16 tile (zero-padded at image borders) — raw copy, no cvt
    const int lane4 = tid & 15;
    const int pg = tid >> 4;
    for (int p = pg; p < 144; p += 16) {
        int pr = p / 12, pc = p - pr * 12;
        int r = th * 8 - 2 + pr, c = tw * 8 - 2 + pc;
        ushort4 u = make_ushort4(0, 0, 0, 0);
        if (r >= 0 && r < 256 && c >= 0 && c < 256)
            u = *(const ushort4*)(h1 + (((size_t)r * 256 + c) * HID + chbase + lane4 * 4));
        *(ushort4*)&tile[pr][pc][lane4 * 4] = u;
    }
    __syncthreads();

    // sliding 5x6 register window down 8 output rows (scalar FMA — R1 form)
    float win[5][6];
    #pragma unroll
    for (int rr = 0; rr < 4; rr++)
        #pragma unroll
        for (int cc = 0; cc < 6; cc++)
            win[rr][cc] = bf2f(tile[rr][c0 + cc][ch]);

    unsigned obase = ((unsigned)(th * 8) * 256u + (unsigned)(tw * 8 + c0)) * (unsigned)HID
                   + (unsigned)(chbase + ch);

    #pragma unroll
    for (int r0 = 0; r0 < 8; r0++) {
        #pragma unroll
        for (int cc = 0; cc < 6; cc++)
            win[(r0 + 4) % 5][cc] = bf2f(tile[r0 + 4][c0 + cc][ch]);
        float s0 = bias, s1 = bias;
        #pragma unroll
        for (int kr = 0; kr < 5; kr++) {
            int ri = (r0 + kr) % 5;
            #pragma unroll
            for (int kc = 0; kc < 5; kc++) {
                float wt = w[kr * 5 + kc];
                s0 = fmaf(win[ri][kc],     wt, s0);
                s1 = fmaf(win[ri][kc + 1], wt, s1);
            }
        }
        const int rc = (r0 + 2) % 5;
        float v0 = win[rc][2] + gelu_f(s0);
        float v1 = win[rc][3] + gelu_f(s1);
        hout[obase]       = f2bf(v0);
        hout[obase + HID] = f2bf(v1);
        obase += 256u * (unsigned)HID;
    }
}

// ---------------- launch ----------------
extern "C" void kernel_launch(void* const* d_in, const int* in_sizes, int n_in,
                              void* d_out, int out_size, void* d_ws, size_t ws_size,
                              hipStream_t stream) {
    const float* x    = (const float*)d_in[0];
    const float* g1   = (const float*)d_in[1];
    const float* be1  = (const float*)d_in[2];
    const float* wq   = (const float*)d_in[3];
    const float* bq   = (const float*)d_in[4];
    const float* wkv  = (const float*)d_in[5];
    const float* bkv  = (const float*)d_in[6];
    const float* btab = (const float*)d_in[7];
    const float* wproj= (const float*)d_in[8];
    const float* bproj= (const float*)d_in[9];
    const float* g2   = (const float*)d_in[10];
    const float* be2  = (const float*)d_in[11];
    const float* w1f  = (const float*)d_in[12];
    const float* b1f  = (const float*)d_in[13];
    const float* dwk  = (const float*)d_in[14];
    const float* dwb  = (const float*)d_in[15];
    const float* w2f  = (const float*)d_in[16];
    const float* b2f  = (const float*)d_in[17];
    float* out = (float*)d_out;

    // workspace layout (bytes), peak ~327.9 MB
    char* ws = (char*)d_ws;
    unsigned short* xnb  = (unsigned short*)(ws);              // xn -> aw (bf16)
    unsigned short* qb   = (unsigned short*)(ws + 50331648);   // q  -> xn2 (bf16)
    unsigned short* kvb  = (unsigned short*)(ws + 100663296);  // kv (bf16)
    unsigned short* h1b  = (unsigned short*)(ws + 125829120);  // h1, one image (bf16)
    unsigned short* hhb  = (unsigned short*)(ws + 226492416);  // h,  one image (bf16)
    unsigned short* qkvT = (unsigned short*)(ws + 327155712);  // [288][192]
    unsigned short* projT= (unsigned short*)(ws + 327266304);  // [192][192]
    unsigned short* w1T  = (unsigned short*)(ws + 327340032);  // [768][192]
    unsigned short* w2T  = (unsigned short*)(ws + 327634944);  // [192][768]

    // 0) weight transpose+cast
    wconv_kernel<<<576, 256, 0, stream>>>(wq, wkv, wproj, w1f, w2f,
                                          qkvT, projT, w1T, w2T);
    // 1) LN1 -> xnb
    ln_kernel<<<NTOK / 4, 256, 0, stream>>>(x, g1, be1, xnb);
    // 2) QKV projection -> qb, kvb   (N=288 = 3 x 96)
    mgemm_kernel<0><<<dim3(3, NTOK / 128), 256, 0, stream>>>(
        xnb, qkvT, bq, bkv, nullptr, qb, kvb, 192, 288);
    // 3) attention -> aw (token-major), overlays xnb
    attn_kernel<<<2048, 384, 0, stream>>>(qb, kvb, btab, xnb);
    // 4) proj + residual -> xattn lives in d_out   (N=192 = 2 x 96)
    mgemm_kernel<1><<<dim3(2, NTOK / 128), 256, 0, stream>>>(
        xnb, projT, bproj, nullptr, x, out, nullptr, 192, 192);
    // 5) LN2 -> xn2b (overlays qb)
    ln_kernel<<<NTOK / 4, 256, 0, stream>>>(out, g2, be2, qb);
    // 6-8) ConvFFN per batch image; FC2 accumulates into d_out
    for (int half = 0; half < 2; half++) {
        const unsigned short* xn2h = qb + (size_t)half * NTOKH * CD;
        float* outh = out + (size_t)half * NTOKH * CD;
        mgemm_kernel<2><<<dim3(8, NTOKH / 128), 256, 0, stream>>>(
            xn2h, w1T, b1f, nullptr, nullptr, h1b, nullptr, 192, 768);
        dwconv_kernel<<<12 * 32 * 32, 256, 0, stream>>>(h1b, dwk, dwb, hhb);
        mgemm_kernel<3><<<dim3(2, NTOKH / 128), 256, 0, stream>>>(
            hhb, w2T, b2f, nullptr, nullptr, outh, nullptr, 768, 192);
    }
}